// Round 4
// baseline (146.196 us; speedup 1.0000x reference)
//
#include <hip/hip_runtime.h>

#define A 10      // attractors
#define D 128     // latent dim
#define LPP 8     // lanes per position
#define QPL 4     // float4 chunks per lane (16 dims / 4)

// Single kernel: 8 lanes per position, 16 dims/lane in registers, attractor
// slices register-resident (10x16 = 160 VGPRs), all 50 iterations in-kernel.
// Per-position reductions via 3-step shfl_xor butterfly over the 8-lane group.
__global__ __launch_bounds__(256, 2) void attractor_sim_kernel(
        const float* __restrict__ pos0,
        const float* __restrict__ att,
        const int* __restrict__ niter,
        float* __restrict__ out,
        int P)
{
    const int t = blockIdx.x * blockDim.x + threadIdx.x;
    const int p = t >> 3;      // position index
    const int l = t & 7;       // slice index within position
    if (p >= P) return;

    const int nt = niter[0];

    const float4* __restrict__ pos4 =
        reinterpret_cast<const float4*>(pos0) + (size_t)p * (D / 4) + l * QPL;
    const float4* __restrict__ att4 = reinterpret_cast<const float4*>(att);
    float4* __restrict__ out4 =
        reinterpret_cast<float4*>(out) + (size_t)p * (D / 4) + l * QPL;

    // my 16 dims of the position (coalesced: consecutive lanes -> consecutive 64B)
    float4 x[QPL];
    #pragma unroll
    for (int q = 0; q < QPL; ++q) x[q] = pos4[q];

    // my 16-dim slice of each attractor, register-resident for the whole run
    float4 av[A][QPL];
    #pragma unroll
    for (int a = 0; a < A; ++a)
        #pragma unroll
        for (int q = 0; q < QPL; ++q) av[a][q] = att4[a * (D / 4) + l * QPL + q];

    // |att_a|^2 once per kernel: per-lane partial + butterfly all-reduce
    float A2[A];
    #pragma unroll
    for (int a = 0; a < A; ++a) {
        float s = 0.f;
        #pragma unroll
        for (int q = 0; q < QPL; ++q) {
            float4 w = av[a][q];
            s = fmaf(w.x, w.x, s); s = fmaf(w.y, w.y, s);
            s = fmaf(w.z, w.z, s); s = fmaf(w.w, w.w, s);
        }
        #pragma unroll
        for (int m = 1; m < LPP; m <<= 1) s += __shfl_xor(s, m);
        A2[a] = s;
    }

    const float c = 0.001f * 0.01f;  // GRAVITY * STEP = 1e-5

    for (int it = 0; it < nt; ++it) {
        // ---- partial |pos|^2 and att_a . pos over my 16 dims ----
        float s2 = 0.f;
        float dot[A];
        #pragma unroll
        for (int a = 0; a < A; ++a) dot[a] = 0.f;

        #pragma unroll
        for (int q = 0; q < QPL; ++q) {
            float4 v = x[q];
            s2 = fmaf(v.x, v.x, s2); s2 = fmaf(v.y, v.y, s2);
            s2 = fmaf(v.z, v.z, s2); s2 = fmaf(v.w, v.w, s2);
            #pragma unroll
            for (int a = 0; a < A; ++a) {
                float4 w = av[a][q];
                float d0 = fmaf(v.x, w.x, dot[a]);
                d0 = fmaf(v.y, w.y, d0);
                d0 = fmaf(v.z, w.z, d0);
                d0 = fmaf(v.w, w.w, d0);
                dot[a] = d0;
            }
        }

        // ---- butterfly all-reduce across the 8 lanes of this position ----
        #pragma unroll
        for (int m = 1; m < LPP; m <<= 1) {
            s2 += __shfl_xor(s2, m);
            #pragma unroll
            for (int a = 0; a < A; ++a) dot[a] += __shfl_xor(dot[a], m);
        }

        // ---- per-attractor coefficient civ_a = G*STEP / (sqrt(d2)+EPS)^3 ----
        float civ[A];
        float s = 0.f;
        #pragma unroll
        for (int a = 0; a < A; ++a) {
            float dist2 = fmaf(-2.f, dot[a], s2 + A2[a]);   // |att-pos|^2
            float r = __builtin_amdgcn_rsqf(dist2);
            float dist = fmaf(dist2, r, 1e-8f);             // sqrt(dist2) + EPS
            float d3 = dist * dist * dist;
            float iv = __builtin_amdgcn_rcpf(d3);
            float cv = c * iv;
            civ[a] = cv;
            s += cv;
        }

        // ---- pos += sum_a civ_a*(att_a - pos) = (f - s*pos), stepped in fp32 ----
        #pragma unroll
        for (int q = 0; q < QPL; ++q) {
            float4 f = make_float4(0.f, 0.f, 0.f, 0.f);
            #pragma unroll
            for (int a = 0; a < A; ++a) {
                float4 w = av[a][q];
                f.x = fmaf(civ[a], w.x, f.x);
                f.y = fmaf(civ[a], w.y, f.y);
                f.z = fmaf(civ[a], w.z, f.z);
                f.w = fmaf(civ[a], w.w, f.w);
            }
            float4 v = x[q];
            v.x += fmaf(-s, v.x, f.x);
            v.y += fmaf(-s, v.y, f.y);
            v.z += fmaf(-s, v.z, f.z);
            v.w += fmaf(-s, v.w, f.w);
            x[q] = v;
        }
    }

    #pragma unroll
    for (int q = 0; q < QPL; ++q) out4[q] = x[q];
}

extern "C" void kernel_launch(void* const* d_in, const int* in_sizes, int n_in,
                              void* d_out, int out_size, void* d_ws, size_t ws_size,
                              hipStream_t stream) {
    const float* pos0 = (const float*)d_in[0];   // embeddings [4,4096,128] fp32
    const float* att  = (const float*)d_in[1];   // attractors [10,128] fp32
    const int*   nit  = (const int*)d_in[2];     // num_iterations (scalar array)
    float* out = (float*)d_out;

    const int P = in_sizes[0] / D;               // 16384 positions

    const int threads = P * LPP;                 // 131072
    hipLaunchKernelGGL(attractor_sim_kernel, dim3((threads + 255) / 256), dim3(256),
                       0, stream, pos0, att, nit, out, P);
}